// Round 1
// baseline (2372.126 us; speedup 1.0000x reference)
//
#include <hip/hip_runtime.h>

#define NN 100000
#define NE 1600000
#define NADJ 2
#define NLAY 3
#define HD 128
#define NG 1024

__device__ __forceinline__ float f4c(const float4 v, int k) {
    return k == 0 ? v.x : (k == 1 ? v.y : (k == 2 ? v.z : v.w));
}

// C[N x 128] = A[N x 128] @ W[128 x 128] (+bias)(+relu). 32 rows per block.
__global__ __launch_bounds__(256) void gemm_nk128(
    const float* __restrict__ A, const float* __restrict__ W,
    float* __restrict__ C, const float* __restrict__ bias, int relu)
{
    __shared__ float sW[128 * 128];   // 64 KB
    __shared__ float sA[32 * 128];    // 16 KB, xor-swizzled in float4 units
    const int t = threadIdx.x;
    const int blk = blockIdx.x;

    const float4* Wv = (const float4*)W;
    float4* sWv = (float4*)sW;
    #pragma unroll
    for (int i = 0; i < 16; ++i) sWv[i * 256 + t] = Wv[i * 256 + t];

    const float4* Av = (const float4*)(A + (size_t)blk * 32 * 128);
    float4* sAv = (float4*)sA;
    #pragma unroll
    for (int i = 0; i < 4; ++i) {
        int f = i * 256 + t;
        int row = f >> 5, c4 = f & 31;
        sAv[row * 32 + (c4 ^ (row >> 2))] = Av[f];
    }
    __syncthreads();

    const int rg = t & 7, cg = t >> 3;   // 8 row-groups x 32 col-groups
    float4 acc[4];
    #pragma unroll
    for (int i = 0; i < 4; ++i) acc[i] = make_float4(0.f, 0.f, 0.f, 0.f);

    #pragma unroll 8
    for (int k0 = 0; k0 < 128; k0 += 4) {
        float4 a[4], b[4];
        #pragma unroll
        for (int i = 0; i < 4; ++i)
            a[i] = sAv[(rg * 4 + i) * 32 + ((k0 >> 2) ^ rg)];
        #pragma unroll
        for (int kk = 0; kk < 4; ++kk)
            b[kk] = sWv[(k0 + kk) * 32 + cg];
        #pragma unroll
        for (int kk = 0; kk < 4; ++kk) {
            #pragma unroll
            for (int i = 0; i < 4; ++i) {
                float av = f4c(a[i], kk);
                acc[i].x = fmaf(av, b[kk].x, acc[i].x);
                acc[i].y = fmaf(av, b[kk].y, acc[i].y);
                acc[i].z = fmaf(av, b[kk].z, acc[i].z);
                acc[i].w = fmaf(av, b[kk].w, acc[i].w);
            }
        }
    }

    float4 bb = make_float4(0.f, 0.f, 0.f, 0.f);
    if (bias) bb = ((const float4*)bias)[cg];
    float4* Cv = (float4*)C;
    #pragma unroll
    for (int i = 0; i < 4; ++i) {
        float4 o = acc[i];
        o.x += bb.x; o.y += bb.y; o.z += bb.z; o.w += bb.w;
        if (relu) {
            o.x = fmaxf(o.x, 0.f); o.y = fmaxf(o.y, 0.f);
            o.z = fmaxf(o.z, 0.f); o.w = fmaxf(o.w, 0.f);
        }
        Cv[((size_t)blk * 32 + rg * 4 + i) * 32 + cg] = o;
    }
}

__global__ void hist_col(const int* __restrict__ col, int* __restrict__ cnt) {
    int e = blockIdx.x * 256 + threadIdx.x;
    if (e < NE) atomicAdd(&cnt[col[e]], 1);
}

__global__ void calc_dis(const int* __restrict__ cnt, float* __restrict__ dis) {
    int i = blockIdx.x * 256 + threadIdx.x;
    if (i < NN) dis[i] = rsqrtf((float)(cnt[i] + 1));   // +1 self loop; deg >= 1
}

// single-block exclusive scan of cnt -> row_ptr (N+1) and cursor copy
__global__ __launch_bounds__(1024) void scan_rowptr(
    const int* __restrict__ cnt, int* __restrict__ row_ptr, int* __restrict__ cursor)
{
    __shared__ int s[1024];
    int tid = threadIdx.x;
    const int chunk = (NN + 1023) / 1024;
    int start = tid * chunk;
    int end = min(start + chunk, NN);
    int sum = 0;
    for (int i = start; i < end; ++i) sum += cnt[i];
    s[tid] = sum;
    __syncthreads();
    for (int off = 1; off < 1024; off <<= 1) {
        int v = 0;
        if (tid >= off) v = s[tid - off];
        __syncthreads();
        s[tid] += v;
        __syncthreads();
    }
    int base = (tid == 0) ? 0 : s[tid - 1];
    for (int i = start; i < end; ++i) {
        row_ptr[i] = base;
        cursor[i] = base;
        base += cnt[i];
    }
    if (tid == 1023) row_ptr[NN] = s[1023];
}

__global__ void scatter_edges(
    const int* __restrict__ row, const int* __restrict__ col,
    const float* __restrict__ dis, int* __restrict__ cursor,
    int* __restrict__ csr_src, float* __restrict__ csr_w)
{
    int e = blockIdx.x * 256 + threadIdx.x;
    if (e >= NE) return;
    int r = row[e], c = col[e];
    int p = atomicAdd(&cursor[c], 1);
    csr_src[p] = r;
    csr_w[p] = dis[r] * dis[c];
}

// out[i] = relu( dis[i]^2 * m[i] + sum_e w_e * m[src_e] ), one wave per node
__global__ __launch_bounds__(256) void agg_relu(
    const float* __restrict__ m, const int* __restrict__ row_ptr,
    const int* __restrict__ csr_src, const float* __restrict__ csr_w,
    const float* __restrict__ dis, float* __restrict__ out)
{
    int node = blockIdx.x * 4 + (threadIdx.x >> 6);
    if (node >= NN) return;
    int lane = threadIdx.x & 63;
    const float2* mv = (const float2*)m;
    float d = dis[node];
    float2 self = mv[(size_t)node * 64 + lane];
    float accx = d * d * self.x;
    float accy = d * d * self.y;
    int e0 = row_ptr[node], e1 = row_ptr[node + 1];
    for (int e = e0; e < e1; ++e) {
        int s = csr_src[e];
        float w = csr_w[e];
        float2 v = mv[(size_t)s * 64 + lane];
        accx = fmaf(w, v.x, accx);
        accy = fmaf(w, v.y, accy);
    }
    float2 o;
    o.x = fmaxf(accx, 0.f);
    o.y = fmaxf(accy, 0.f);
    ((float2*)out)[(size_t)node * 64 + lane] = o;
}

// pooled[batch[n]][aoff + c] += h[n][c], exploiting sorted batch
__global__ __launch_bounds__(128) void pool_add(
    const float* __restrict__ h, const int* __restrict__ batch,
    float* __restrict__ pooled, int aoff)
{
    int c = threadIdx.x;
    int n0 = blockIdx.x * 64;
    int nend = min(n0 + 64, NN);
    int cur = batch[n0];
    float acc = 0.f;
    for (int n = n0; n < nend; ++n) {
        int g = batch[n];
        if (g != cur) {
            atomicAdd(&pooled[(size_t)cur * 256 + aoff + c], acc);
            acc = 0.f;
            cur = g;
        }
        acc += h[(size_t)n * 128 + c];
    }
    atomicAdd(&pooled[(size_t)cur * 256 + aoff + c], acc);
}

// out[g] = relu(pooled[g] @ w1 + b1) @ w2 + b2
__global__ __launch_bounds__(128) void head(
    const float* __restrict__ pooled,
    const float* __restrict__ w1, const float* __restrict__ b1,
    const float* __restrict__ w2, const float* __restrict__ b2,
    float* __restrict__ out)
{
    __shared__ float sp[256];
    __shared__ float sg[128];
    int g = blockIdx.x, t = threadIdx.x;
    sp[t] = pooled[(size_t)g * 256 + t];
    sp[t + 128] = pooled[(size_t)g * 256 + 128 + t];
    __syncthreads();
    float acc = b1[t];
    #pragma unroll 8
    for (int k = 0; k < 256; ++k) acc = fmaf(sp[k], w1[k * 128 + t], acc);
    sg[t] = fmaxf(acc, 0.f) * w2[t];
    __syncthreads();
    for (int s2 = 64; s2 > 0; s2 >>= 1) {
        if (t < s2) sg[t] += sg[t + s2];
        __syncthreads();
    }
    if (t == 0) out[g] = sg[0] + b2[0];
}

extern "C" void kernel_launch(void* const* d_in, const int* in_sizes, int n_in,
                              void* d_out, int out_size, void* d_ws, size_t ws_size,
                              hipStream_t stream) {
    const float* x      = (const float*)d_in[0];
    const int*   ei     = (const int*)d_in[1];
    const int*   batch  = (const int*)d_in[2];
    const float* lin0_w = (const float*)d_in[3];
    const float* lin0_b = (const float*)d_in[4];
    const float* conv_w = (const float*)d_in[5];
    const float* lin1_w = (const float*)d_in[6];
    const float* lin1_b = (const float*)d_in[7];
    const float* lin2_w = (const float*)d_in[8];
    const float* lin2_b = (const float*)d_in[9];
    float* out = (float*)d_out;

    const size_t NB = (size_t)NN * HD;
    float* x0     = (float*)d_ws;
    float* bufA   = x0 + NB;
    float* bufB   = bufA + NB;
    float* pooled = bufB + NB;
    int*   cnt     = (int*)(pooled + (size_t)NG * 256);
    int*   row_ptr = cnt + NN;
    int*   cursor  = row_ptr + NN + 1;
    float* dis     = (float*)(cursor + NN);
    int*   csr_src = (int*)(dis + NN);
    float* csr_w   = (float*)(csr_src + NE);

    hipMemsetAsync(pooled, 0, (size_t)NG * 256 * sizeof(float), stream);

    // x0 = relu(x @ lin0_w + lin0_b)
    gemm_nk128<<<NN / 32, 256, 0, stream>>>(x, lin0_w, x0, lin0_b, 1);

    for (int a = 0; a < NADJ; ++a) {
        const int* row = ei + (size_t)a * 2 * NE;
        const int* col = row + NE;

        hipMemsetAsync(cnt, 0, NN * sizeof(int), stream);
        hist_col<<<(NE + 255) / 256, 256, 0, stream>>>(col, cnt);
        scan_rowptr<<<1, 1024, 0, stream>>>(cnt, row_ptr, cursor);
        calc_dis<<<(NN + 255) / 256, 256, 0, stream>>>(cnt, dis);
        scatter_edges<<<(NE + 255) / 256, 256, 0, stream>>>(row, col, dis, cursor,
                                                            csr_src, csr_w);

        const float* h = x0;
        for (int l = 0; l < NLAY; ++l) {
            const float* W = conv_w + ((size_t)a * NLAY + l) * HD * HD;
            gemm_nk128<<<NN / 32, 256, 0, stream>>>(h, W, bufA, nullptr, 0);
            agg_relu<<<(NN + 3) / 4, 256, 0, stream>>>(bufA, row_ptr, csr_src,
                                                       csr_w, dis, bufB);
            h = bufB;
        }
        pool_add<<<(NN + 63) / 64, 128, 0, stream>>>(bufB, batch, pooled, a * HD);
    }

    head<<<NG, 128, 0, stream>>>(pooled, lin1_w, lin1_b, lin2_w, lin2_b, out);
}

// Round 2
// 1937.742 us; speedup vs baseline: 1.2242x; 1.2242x over previous
//
#include <hip/hip_runtime.h>

#define NN 100000
#define NE 1600000
#define NADJ 2
#define NLAY 3
#define HD 128
#define NG 1024

#define SCAN_BLOCKS ((NN + 255) / 256)   // 391

__device__ __forceinline__ float f4c(const float4 v, int k) {
    return k == 0 ? v.x : (k == 1 ? v.y : (k == 2 ? v.z : v.w));
}

// C[N x 128] = A[N x 128] @ W[128 x 128] (+bias)(+relu). 32 rows per block.
__global__ __launch_bounds__(256) void gemm_nk128(
    const float* __restrict__ A, const float* __restrict__ W,
    float* __restrict__ C, const float* __restrict__ bias, int relu)
{
    __shared__ float sW[128 * 128];   // 64 KB
    __shared__ float sA[32 * 128];    // 16 KB, xor-swizzled in float4 units
    const int t = threadIdx.x;
    const int blk = blockIdx.x;

    const float4* Wv = (const float4*)W;
    float4* sWv = (float4*)sW;
    #pragma unroll
    for (int i = 0; i < 16; ++i) sWv[i * 256 + t] = Wv[i * 256 + t];

    const float4* Av = (const float4*)(A + (size_t)blk * 32 * 128);
    float4* sAv = (float4*)sA;
    #pragma unroll
    for (int i = 0; i < 4; ++i) {
        int f = i * 256 + t;
        int row = f >> 5, c4 = f & 31;
        sAv[row * 32 + (c4 ^ (row >> 2))] = Av[f];
    }
    __syncthreads();

    const int rg = t & 7, cg = t >> 3;   // 8 row-groups x 32 col-groups
    float4 acc[4];
    #pragma unroll
    for (int i = 0; i < 4; ++i) acc[i] = make_float4(0.f, 0.f, 0.f, 0.f);

    #pragma unroll 8
    for (int k0 = 0; k0 < 128; k0 += 4) {
        float4 a[4], b[4];
        #pragma unroll
        for (int i = 0; i < 4; ++i)
            a[i] = sAv[(rg * 4 + i) * 32 + ((k0 >> 2) ^ rg)];
        #pragma unroll
        for (int kk = 0; kk < 4; ++kk)
            b[kk] = sWv[(k0 + kk) * 32 + cg];
        #pragma unroll
        for (int kk = 0; kk < 4; ++kk) {
            #pragma unroll
            for (int i = 0; i < 4; ++i) {
                float av = f4c(a[i], kk);
                acc[i].x = fmaf(av, b[kk].x, acc[i].x);
                acc[i].y = fmaf(av, b[kk].y, acc[i].y);
                acc[i].z = fmaf(av, b[kk].z, acc[i].z);
                acc[i].w = fmaf(av, b[kk].w, acc[i].w);
            }
        }
    }

    float4 bb = make_float4(0.f, 0.f, 0.f, 0.f);
    if (bias) bb = ((const float4*)bias)[cg];
    float4* Cv = (float4*)C;
    #pragma unroll
    for (int i = 0; i < 4; ++i) {
        float4 o = acc[i];
        o.x += bb.x; o.y += bb.y; o.z += bb.z; o.w += bb.w;
        if (relu) {
            o.x = fmaxf(o.x, 0.f); o.y = fmaxf(o.y, 0.f);
            o.z = fmaxf(o.z, 0.f); o.w = fmaxf(o.w, 0.f);
        }
        Cv[((size_t)blk * 32 + rg * 4 + i) * 32 + cg] = o;
    }
}

__global__ void hist_col(const int* __restrict__ col, int* __restrict__ cnt) {
    int e = blockIdx.x * 256 + threadIdx.x;
    if (e < NE) atomicAdd(&cnt[col[e]], 1);
}

// ---- hierarchical scan: cnt -> row_ptr/cursor (exclusive), dis = rsqrt(cnt+1)

__global__ __launch_bounds__(256) void block_sums(
    const int* __restrict__ cnt, int* __restrict__ bsum)
{
    __shared__ int ws[4];
    int i = blockIdx.x * 256 + threadIdx.x;
    int v = (i < NN) ? cnt[i] : 0;
    #pragma unroll
    for (int off = 32; off > 0; off >>= 1) v += __shfl_xor(v, off);
    int wid = threadIdx.x >> 6;
    if ((threadIdx.x & 63) == 0) ws[wid] = v;
    __syncthreads();
    if (threadIdx.x == 0) bsum[blockIdx.x] = ws[0] + ws[1] + ws[2] + ws[3];
}

__global__ __launch_bounds__(512) void scan_bsums(int* __restrict__ bsum)
{
    __shared__ int s[512];
    int t = threadIdx.x;
    int v = (t < SCAN_BLOCKS) ? bsum[t] : 0;
    s[t] = v;
    __syncthreads();
    #pragma unroll
    for (int off = 1; off < 512; off <<= 1) {
        int u = (t >= off) ? s[t - off] : 0;
        __syncthreads();
        s[t] += u;
        __syncthreads();
    }
    if (t < SCAN_BLOCKS) bsum[t] = s[t] - v;   // exclusive
}

__global__ __launch_bounds__(256) void write_rowptr(
    const int* __restrict__ cnt, const int* __restrict__ bsum,
    int* __restrict__ row_ptr, int* __restrict__ cursor,
    float* __restrict__ dis)
{
    __shared__ int s[256];
    int t = threadIdx.x;
    int i = blockIdx.x * 256 + t;
    int v = (i < NN) ? cnt[i] : 0;
    s[t] = v;
    __syncthreads();
    #pragma unroll
    for (int off = 1; off < 256; off <<= 1) {
        int u = (t >= off) ? s[t - off] : 0;
        __syncthreads();
        s[t] += u;
        __syncthreads();
    }
    if (i < NN) {
        int excl = bsum[blockIdx.x] + s[t] - v;
        row_ptr[i] = excl;
        cursor[i] = excl;
        dis[i] = rsqrtf((float)(v + 1));   // +1 self loop
        if (i == NN - 1) row_ptr[NN] = excl + v;
    }
}

__global__ void scatter_edges(
    const int* __restrict__ row, const int* __restrict__ col,
    const float* __restrict__ dis, int* __restrict__ cursor,
    int* __restrict__ csr_src, float* __restrict__ csr_w)
{
    int e = blockIdx.x * 256 + threadIdx.x;
    if (e >= NE) return;
    int r = row[e], c = col[e];
    int p = atomicAdd(&cursor[c], 1);
    csr_src[p] = r;
    csr_w[p] = dis[r] * dis[c];
}

// out[i] = relu( dis[i]^2 * m[i] + sum_e w_e * m[src_e] ), one wave per node
__global__ __launch_bounds__(256) void agg_relu(
    const float* __restrict__ m, const int* __restrict__ row_ptr,
    const int* __restrict__ csr_src, const float* __restrict__ csr_w,
    const float* __restrict__ dis, float* __restrict__ out)
{
    int node = blockIdx.x * 4 + (threadIdx.x >> 6);
    if (node >= NN) return;
    int lane = threadIdx.x & 63;
    const float2* mv = (const float2*)m;
    float d = dis[node];
    float2 self = mv[(size_t)node * 64 + lane];
    float accx = d * d * self.x;
    float accy = d * d * self.y;
    int e0 = row_ptr[node], e1 = row_ptr[node + 1];
    for (int e = e0; e < e1; ++e) {
        int s = csr_src[e];
        float w = csr_w[e];
        float2 v = mv[(size_t)s * 64 + lane];
        accx = fmaf(w, v.x, accx);
        accy = fmaf(w, v.y, accy);
    }
    float2 o;
    o.x = fmaxf(accx, 0.f);
    o.y = fmaxf(accy, 0.f);
    ((float2*)out)[(size_t)node * 64 + lane] = o;
}

// pooled[batch[n]][aoff + c] += h[n][c], exploiting sorted batch
__global__ __launch_bounds__(128) void pool_add(
    const float* __restrict__ h, const int* __restrict__ batch,
    float* __restrict__ pooled, int aoff)
{
    int c = threadIdx.x;
    int n0 = blockIdx.x * 64;
    int nend = min(n0 + 64, NN);
    int cur = batch[n0];
    float acc = 0.f;
    for (int n = n0; n < nend; ++n) {
        int g = batch[n];
        if (g != cur) {
            atomicAdd(&pooled[(size_t)cur * 256 + aoff + c], acc);
            acc = 0.f;
            cur = g;
        }
        acc += h[(size_t)n * 128 + c];
    }
    atomicAdd(&pooled[(size_t)cur * 256 + aoff + c], acc);
}

// out[g] = relu(pooled[g] @ w1 + b1) @ w2 + b2
__global__ __launch_bounds__(128) void head(
    const float* __restrict__ pooled,
    const float* __restrict__ w1, const float* __restrict__ b1,
    const float* __restrict__ w2, const float* __restrict__ b2,
    float* __restrict__ out)
{
    __shared__ float sp[256];
    __shared__ float sg[128];
    int g = blockIdx.x, t = threadIdx.x;
    sp[t] = pooled[(size_t)g * 256 + t];
    sp[t + 128] = pooled[(size_t)g * 256 + 128 + t];
    __syncthreads();
    float acc = b1[t];
    #pragma unroll 8
    for (int k = 0; k < 256; ++k) acc = fmaf(sp[k], w1[k * 128 + t], acc);
    sg[t] = fmaxf(acc, 0.f) * w2[t];
    __syncthreads();
    for (int s2 = 64; s2 > 0; s2 >>= 1) {
        if (t < s2) sg[t] += sg[t + s2];
        __syncthreads();
    }
    if (t == 0) out[g] = sg[0] + b2[0];
}

extern "C" void kernel_launch(void* const* d_in, const int* in_sizes, int n_in,
                              void* d_out, int out_size, void* d_ws, size_t ws_size,
                              hipStream_t stream) {
    const float* x      = (const float*)d_in[0];
    const int*   ei     = (const int*)d_in[1];
    const int*   batch  = (const int*)d_in[2];
    const float* lin0_w = (const float*)d_in[3];
    const float* lin0_b = (const float*)d_in[4];
    const float* conv_w = (const float*)d_in[5];
    const float* lin1_w = (const float*)d_in[6];
    const float* lin1_b = (const float*)d_in[7];
    const float* lin2_w = (const float*)d_in[8];
    const float* lin2_b = (const float*)d_in[9];
    float* out = (float*)d_out;

    const size_t NB = (size_t)NN * HD;
    float* x0     = (float*)d_ws;
    float* bufA   = x0 + NB;
    float* bufB   = bufA + NB;
    float* pooled = bufB + NB;
    int*   cnt     = (int*)(pooled + (size_t)NG * 256);
    int*   row_ptr = cnt + NN;
    int*   cursor  = row_ptr + NN + 1;
    float* dis     = (float*)(cursor + NN);
    int*   csr_src = (int*)(dis + NN);
    float* csr_w   = (float*)(csr_src + NE);
    int*   bsum    = (int*)(csr_w + NE);

    hipMemsetAsync(pooled, 0, (size_t)NG * 256 * sizeof(float), stream);

    // x0 = relu(x @ lin0_w + lin0_b)
    gemm_nk128<<<NN / 32, 256, 0, stream>>>(x, lin0_w, x0, lin0_b, 1);

    for (int a = 0; a < NADJ; ++a) {
        const int* row = ei + (size_t)a * 2 * NE;
        const int* col = row + NE;

        hipMemsetAsync(cnt, 0, NN * sizeof(int), stream);
        hist_col<<<(NE + 255) / 256, 256, 0, stream>>>(col, cnt);
        block_sums<<<SCAN_BLOCKS, 256, 0, stream>>>(cnt, bsum);
        scan_bsums<<<1, 512, 0, stream>>>(bsum);
        write_rowptr<<<SCAN_BLOCKS, 256, 0, stream>>>(cnt, bsum, row_ptr,
                                                      cursor, dis);
        scatter_edges<<<(NE + 255) / 256, 256, 0, stream>>>(row, col, dis, cursor,
                                                            csr_src, csr_w);

        const float* h = x0;
        for (int l = 0; l < NLAY; ++l) {
            const float* W = conv_w + ((size_t)a * NLAY + l) * HD * HD;
            gemm_nk128<<<NN / 32, 256, 0, stream>>>(h, W, bufA, nullptr, 0);
            agg_relu<<<(NN + 3) / 4, 256, 0, stream>>>(bufA, row_ptr, csr_src,
                                                       csr_w, dis, bufB);
            h = bufB;
        }
        pool_add<<<(NN + 63) / 64, 128, 0, stream>>>(bufB, batch, pooled, a * HD);
    }

    head<<<NG, 128, 0, stream>>>(pooled, lin1_w, lin1_b, lin2_w, lin2_b, out);
}

// Round 3
// 1667.321 us; speedup vs baseline: 1.4227x; 1.1622x over previous
//
#include <hip/hip_runtime.h>

#define NN 100000
#define NE 1600000
#define NADJ 2
#define NLAY 3
#define HD 128
#define NG 1024

#define SCAN_BLOCKS ((NN + 255) / 256)   // 391

__device__ __forceinline__ float f4c(const float4 v, int k) {
    return k == 0 ? v.x : (k == 1 ? v.y : (k == 2 ? v.z : v.w));
}

// C[N x 128] = A[N x 128] @ W[128 x 128] (+bias)(+relu). 32 rows per block.
__global__ __launch_bounds__(256) void gemm_nk128(
    const float* __restrict__ A, const float* __restrict__ W,
    float* __restrict__ C, const float* __restrict__ bias, int relu)
{
    __shared__ float sW[128 * 128];   // 64 KB
    __shared__ float sA[32 * 128];    // 16 KB, xor-swizzled in float4 units
    const int t = threadIdx.x;
    const int blk = blockIdx.x;

    const float4* Wv = (const float4*)W;
    float4* sWv = (float4*)sW;
    #pragma unroll
    for (int i = 0; i < 16; ++i) sWv[i * 256 + t] = Wv[i * 256 + t];

    const float4* Av = (const float4*)(A + (size_t)blk * 32 * 128);
    float4* sAv = (float4*)sA;
    #pragma unroll
    for (int i = 0; i < 4; ++i) {
        int f = i * 256 + t;
        int row = f >> 5, c4 = f & 31;
        sAv[row * 32 + (c4 ^ (row >> 2))] = Av[f];
    }
    __syncthreads();

    const int rg = t & 7, cg = t >> 3;   // 8 row-groups x 32 col-groups
    float4 acc[4];
    #pragma unroll
    for (int i = 0; i < 4; ++i) acc[i] = make_float4(0.f, 0.f, 0.f, 0.f);

    #pragma unroll 8
    for (int k0 = 0; k0 < 128; k0 += 4) {
        float4 a[4], b[4];
        #pragma unroll
        for (int i = 0; i < 4; ++i)
            a[i] = sAv[(rg * 4 + i) * 32 + ((k0 >> 2) ^ rg)];
        #pragma unroll
        for (int kk = 0; kk < 4; ++kk)
            b[kk] = sWv[(k0 + kk) * 32 + cg];
        #pragma unroll
        for (int kk = 0; kk < 4; ++kk) {
            #pragma unroll
            for (int i = 0; i < 4; ++i) {
                float av = f4c(a[i], kk);
                acc[i].x = fmaf(av, b[kk].x, acc[i].x);
                acc[i].y = fmaf(av, b[kk].y, acc[i].y);
                acc[i].z = fmaf(av, b[kk].z, acc[i].z);
                acc[i].w = fmaf(av, b[kk].w, acc[i].w);
            }
        }
    }

    float4 bb = make_float4(0.f, 0.f, 0.f, 0.f);
    if (bias) bb = ((const float4*)bias)[cg];
    float4* Cv = (float4*)C;
    #pragma unroll
    for (int i = 0; i < 4; ++i) {
        float4 o = acc[i];
        o.x += bb.x; o.y += bb.y; o.z += bb.z; o.w += bb.w;
        if (relu) {
            o.x = fmaxf(o.x, 0.f); o.y = fmaxf(o.y, 0.f);
            o.z = fmaxf(o.z, 0.f); o.w = fmaxf(o.w, 0.f);
        }
        Cv[((size_t)blk * 32 + rg * 4 + i) * 32 + cg] = o;
    }
}

__global__ void hist_col(const int* __restrict__ col, int* __restrict__ cnt) {
    int e = blockIdx.x * 256 + threadIdx.x;
    if (e < NE) atomicAdd(&cnt[col[e]], 1);
}

// ---- hierarchical scan: cnt -> row_ptr/cursor (exclusive), dis = rsqrt(cnt+1)

__global__ __launch_bounds__(256) void block_sums(
    const int* __restrict__ cnt, int* __restrict__ bsum)
{
    __shared__ int ws[4];
    int i = blockIdx.x * 256 + threadIdx.x;
    int v = (i < NN) ? cnt[i] : 0;
    #pragma unroll
    for (int off = 32; off > 0; off >>= 1) v += __shfl_xor(v, off);
    int wid = threadIdx.x >> 6;
    if ((threadIdx.x & 63) == 0) ws[wid] = v;
    __syncthreads();
    if (threadIdx.x == 0) bsum[blockIdx.x] = ws[0] + ws[1] + ws[2] + ws[3];
}

__global__ __launch_bounds__(512) void scan_bsums(int* __restrict__ bsum)
{
    __shared__ int s[512];
    int t = threadIdx.x;
    int v = (t < SCAN_BLOCKS) ? bsum[t] : 0;
    s[t] = v;
    __syncthreads();
    #pragma unroll
    for (int off = 1; off < 512; off <<= 1) {
        int u = (t >= off) ? s[t - off] : 0;
        __syncthreads();
        s[t] += u;
        __syncthreads();
    }
    if (t < SCAN_BLOCKS) bsum[t] = s[t] - v;   // exclusive
}

__global__ __launch_bounds__(256) void write_rowptr(
    const int* __restrict__ cnt, const int* __restrict__ bsum,
    int* __restrict__ row_ptr, int* __restrict__ cursor,
    float* __restrict__ dis)
{
    __shared__ int s[256];
    int t = threadIdx.x;
    int i = blockIdx.x * 256 + t;
    int v = (i < NN) ? cnt[i] : 0;
    s[t] = v;
    __syncthreads();
    #pragma unroll
    for (int off = 1; off < 256; off <<= 1) {
        int u = (t >= off) ? s[t - off] : 0;
        __syncthreads();
        s[t] += u;
        __syncthreads();
    }
    if (i < NN) {
        int excl = bsum[blockIdx.x] + s[t] - v;
        row_ptr[i] = excl;
        cursor[i] = excl;
        dis[i] = rsqrtf((float)(v + 1));   // +1 self loop
        if (i == NN - 1) row_ptr[NN] = excl + v;
    }
}

__global__ void scatter_edges(
    const int* __restrict__ row, const int* __restrict__ col,
    const float* __restrict__ dis, int* __restrict__ cursor,
    int* __restrict__ csr_src, float* __restrict__ csr_w)
{
    int e = blockIdx.x * 256 + threadIdx.x;
    if (e >= NE) return;
    int r = row[e], c = col[e];
    int p = atomicAdd(&cursor[c], 1);
    csr_src[p] = r;
    csr_w[p] = dis[r] * dis[c];
}

// out[i] = relu( dis[i]^2 * m[i] + sum_e w_e * m[src_e] ), one wave per node.
// Edge loop unrolled x8 so 8 independent 512B row-gathers are in flight
// (was latency-bound at ~1 outstanding load/wave -> 169us/dispatch).
__global__ __launch_bounds__(256) void agg_relu(
    const float* __restrict__ m, const int* __restrict__ row_ptr,
    const int* __restrict__ csr_src, const float* __restrict__ csr_w,
    const float* __restrict__ dis, float* __restrict__ out)
{
    int node = blockIdx.x * 4 + (threadIdx.x >> 6);
    if (node >= NN) return;
    int lane = threadIdx.x & 63;
    const float2* mv = (const float2*)m;
    float d = dis[node];
    float2 self = mv[(size_t)node * 64 + lane];
    float accx = d * d * self.x;
    float accy = d * d * self.y;
    int e0 = row_ptr[node], e1 = row_ptr[node + 1];

    int e = e0;
    #define UN 8
    for (; e + UN <= e1; e += UN) {
        int   ss[UN];
        float ww[UN];
        #pragma unroll
        for (int u = 0; u < UN; ++u) {
            ss[u] = csr_src[e + u];
            ww[u] = csr_w[e + u];
        }
        float2 vv[UN];
        #pragma unroll
        for (int u = 0; u < UN; ++u)
            vv[u] = mv[(size_t)ss[u] * 64 + lane];
        #pragma unroll
        for (int u = 0; u < UN; ++u) {
            accx = fmaf(ww[u], vv[u].x, accx);
            accy = fmaf(ww[u], vv[u].y, accy);
        }
    }
    #undef UN
    for (; e < e1; ++e) {
        int s = csr_src[e];
        float w = csr_w[e];
        float2 v = mv[(size_t)s * 64 + lane];
        accx = fmaf(w, v.x, accx);
        accy = fmaf(w, v.y, accy);
    }

    float2 o;
    o.x = fmaxf(accx, 0.f);
    o.y = fmaxf(accy, 0.f);
    ((float2*)out)[(size_t)node * 64 + lane] = o;
}

// pooled[batch[n]][aoff + c] += h[n][c], exploiting sorted batch
__global__ __launch_bounds__(128) void pool_add(
    const float* __restrict__ h, const int* __restrict__ batch,
    float* __restrict__ pooled, int aoff)
{
    int c = threadIdx.x;
    int n0 = blockIdx.x * 64;
    int nend = min(n0 + 64, NN);
    int cur = batch[n0];
    float acc = 0.f;
    for (int n = n0; n < nend; ++n) {
        int g = batch[n];
        if (g != cur) {
            atomicAdd(&pooled[(size_t)cur * 256 + aoff + c], acc);
            acc = 0.f;
            cur = g;
        }
        acc += h[(size_t)n * 128 + c];
    }
    atomicAdd(&pooled[(size_t)cur * 256 + aoff + c], acc);
}

// out[g] = relu(pooled[g] @ w1 + b1) @ w2 + b2
__global__ __launch_bounds__(128) void head(
    const float* __restrict__ pooled,
    const float* __restrict__ w1, const float* __restrict__ b1,
    const float* __restrict__ w2, const float* __restrict__ b2,
    float* __restrict__ out)
{
    __shared__ float sp[256];
    __shared__ float sg[128];
    int g = blockIdx.x, t = threadIdx.x;
    sp[t] = pooled[(size_t)g * 256 + t];
    sp[t + 128] = pooled[(size_t)g * 256 + 128 + t];
    __syncthreads();
    float acc = b1[t];
    #pragma unroll 8
    for (int k = 0; k < 256; ++k) acc = fmaf(sp[k], w1[k * 128 + t], acc);
    sg[t] = fmaxf(acc, 0.f) * w2[t];
    __syncthreads();
    for (int s2 = 64; s2 > 0; s2 >>= 1) {
        if (t < s2) sg[t] += sg[t + s2];
        __syncthreads();
    }
    if (t == 0) out[g] = sg[0] + b2[0];
}

extern "C" void kernel_launch(void* const* d_in, const int* in_sizes, int n_in,
                              void* d_out, int out_size, void* d_ws, size_t ws_size,
                              hipStream_t stream) {
    const float* x      = (const float*)d_in[0];
    const int*   ei     = (const int*)d_in[1];
    const int*   batch  = (const int*)d_in[2];
    const float* lin0_w = (const float*)d_in[3];
    const float* lin0_b = (const float*)d_in[4];
    const float* conv_w = (const float*)d_in[5];
    const float* lin1_w = (const float*)d_in[6];
    const float* lin1_b = (const float*)d_in[7];
    const float* lin2_w = (const float*)d_in[8];
    const float* lin2_b = (const float*)d_in[9];
    float* out = (float*)d_out;

    const size_t NB = (size_t)NN * HD;
    float* x0     = (float*)d_ws;
    float* bufA   = x0 + NB;
    float* bufB   = bufA + NB;
    float* pooled = bufB + NB;
    int*   cnt     = (int*)(pooled + (size_t)NG * 256);
    int*   row_ptr = cnt + NN;
    int*   cursor  = row_ptr + NN + 1;
    float* dis     = (float*)(cursor + NN);
    int*   csr_src = (int*)(dis + NN);
    float* csr_w   = (float*)(csr_src + NE);
    int*   bsum    = (int*)(csr_w + NE);

    hipMemsetAsync(pooled, 0, (size_t)NG * 256 * sizeof(float), stream);

    // x0 = relu(x @ lin0_w + lin0_b)
    gemm_nk128<<<NN / 32, 256, 0, stream>>>(x, lin0_w, x0, lin0_b, 1);

    for (int a = 0; a < NADJ; ++a) {
        const int* row = ei + (size_t)a * 2 * NE;
        const int* col = row + NE;

        hipMemsetAsync(cnt, 0, NN * sizeof(int), stream);
        hist_col<<<(NE + 255) / 256, 256, 0, stream>>>(col, cnt);
        block_sums<<<SCAN_BLOCKS, 256, 0, stream>>>(cnt, bsum);
        scan_bsums<<<1, 512, 0, stream>>>(bsum);
        write_rowptr<<<SCAN_BLOCKS, 256, 0, stream>>>(cnt, bsum, row_ptr,
                                                      cursor, dis);
        scatter_edges<<<(NE + 255) / 256, 256, 0, stream>>>(row, col, dis, cursor,
                                                            csr_src, csr_w);

        const float* h = x0;
        for (int l = 0; l < NLAY; ++l) {
            const float* W = conv_w + ((size_t)a * NLAY + l) * HD * HD;
            gemm_nk128<<<NN / 32, 256, 0, stream>>>(h, W, bufA, nullptr, 0);
            agg_relu<<<(NN + 3) / 4, 256, 0, stream>>>(bufA, row_ptr, csr_src,
                                                       csr_w, dis, bufB);
            h = bufB;
        }
        pool_add<<<(NN + 63) / 64, 128, 0, stream>>>(bufB, batch, pooled, a * HD);
    }

    head<<<NG, 128, 0, stream>>>(pooled, lin1_w, lin1_b, lin2_w, lin2_b, out);
}